// Round 7
// baseline (789.303 us; speedup 1.0000x reference)
//
#include <hip/hip_runtime.h>

// DigitCaps routing, single persistent kernel (+ tiny barrier-init kernel).
// B=512, R=1152, J=10, O=16, I=8, JO=160, K=R*I=9216.
// s[b,jo]    = sum_k x[b,k] * Wc[k,jo],  Wc[(r,i),(j,o)] = W[r,j,o,i]*c[r,j]
// v          = s*|s|/(1+s^2)
// bias[r,j] += (1/B) sum_{i,o} W[r,j,o,i] * M[(r,i),(j,o)],  M = x_r^T @ v
// c          = softmax_r(bias)
//
// r6 lesson: 12 serialized dispatches cost more than the compute; r5 lesson:
// never shrink the grid below the CU count. So: ONE kernel, 256 blocks x 256
// threads (>=3 blocks/CU capacity -> all co-resident, hand-rolled grid barrier
// is deadlock-free), phases = r4's proven shapes, 13 device-scope barriers.
// All reductions fixed-order -> deterministic.

#define B_   512
#define R_   1152
#define JO_  160
#define K_   9216
#define KS_  32
#define SPK_ 9
#define NBLK 256
#define NTHR 256

typedef __attribute__((ext_vector_type(4))) float f32x4;
typedef __attribute__((ext_vector_type(8))) short bf16x8;

__device__ __forceinline__ short f2bf(float f) {
  unsigned int u = __float_as_uint(f);
  unsigned int r = (u + 0x7FFFu + ((u >> 16) & 1u)) >> 16;
  return (short)r;
}

__global__ void barinit_kernel(unsigned* __restrict__ bar) {
  if (threadIdx.x < 2) bar[threadIdx.x] = 0u;
}

// generation barrier: bar[0]=count, bar[1]=gen. Device(AGENT)-scope atomics
// handle cross-XCD; last arriver resets count then release-bumps gen.
__device__ __forceinline__ void grid_bar(unsigned* bar) {
  __syncthreads();
  if (threadIdx.x == 0) {
    __threadfence();
    unsigned g =
        __hip_atomic_load(bar + 1, __ATOMIC_RELAXED, __HIP_MEMORY_SCOPE_AGENT);
    unsigned a = __hip_atomic_fetch_add(bar, 1u, __ATOMIC_ACQ_REL,
                                        __HIP_MEMORY_SCOPE_AGENT);
    if (a == NBLK - 1) {
      __hip_atomic_store(bar, 0u, __ATOMIC_RELAXED, __HIP_MEMORY_SCOPE_AGENT);
      __hip_atomic_fetch_add(bar + 1, 1u, __ATOMIC_RELEASE,
                             __HIP_MEMORY_SCOPE_AGENT);
    } else {
      while (__hip_atomic_load(bar + 1, __ATOMIC_ACQUIRE,
                               __HIP_MEMORY_SCOPE_AGENT) == g)
        __builtin_amdgcn_s_sleep(1);
    }
    __threadfence();
  }
  __syncthreads();
}

__global__ __launch_bounds__(NTHR) void digitcaps_kernel(
    const float* __restrict__ x, const float* __restrict__ W,
    short* __restrict__ xaf, short* __restrict__ xtf,
    short* __restrict__ wcf, float* __restrict__ part,
    short* __restrict__ vfrag, float* __restrict__ bias,
    float* __restrict__ mz, float* __restrict__ out,
    unsigned* __restrict__ bar) {
  __shared__ char smraw[46336];
  float* Msm = (float*)smraw;        // [4][16][176] = 45056 B (agree)
  float* agred = Msm + 4 * 16 * 176; // [320] (agree)
  float* vsm = (float*)smraw;        // [32][17] (squash)
  float* stred = (float*)smraw;      // [256] (stat)

  const int tid = threadIdx.x;
  const int bid = blockIdx.x;
  const int gtid = bid * NTHR + tid;  // < 65536
  const int w = tid >> 6, lane = tid & 63;

  // ---- P0: build xaf (s-GEMM A-fragments), xtf (agree A-fragments), zero bias
  if (gtid < R_ * 10) bias[gtid] = 0.0f;
#pragma unroll
  for (int q = 0; q < 9; ++q) {
    int gid = q * 65536 + gtid;  // < 589824
    int l = gid & 63, f = gid >> 6;
    int ks = f % 288, m16 = f / 288;
    int row = m16 * 16 + (l & 15);
    int k0 = ks * 32 + (l >> 4) * 8;
    const float4* p = (const float4*)(x + (size_t)row * K_ + k0);
    float4 a = p[0], b = p[1];
    bf16x8 pk;
    pk[0] = f2bf(a.x); pk[1] = f2bf(a.y); pk[2] = f2bf(a.z); pk[3] = f2bf(a.w);
    pk[4] = f2bf(b.x); pk[5] = f2bf(b.y); pk[6] = f2bf(b.z); pk[7] = f2bf(b.w);
    ((bf16x8*)xaf)[gid] = pk;
  }
#pragma unroll
  for (int q = 0; q < 9; ++q) {
    int gid = q * 65536 + gtid;  // < 589824
    int l = gid & 63, f = gid >> 6;
    int kb = f & 15, rp = f >> 4;
    int b0 = kb * 32 + (l >> 4) * 8;
    const float* p = x + (size_t)b0 * K_ + rp * 16 + (l & 15);
    bf16x8 pk;
#pragma unroll
    for (int t = 0; t < 8; ++t) pk[t] = f2bf(p[(size_t)t * K_]);
    ((bf16x8*)xtf)[gid] = pk;
  }
  grid_bar(bar);

  for (int it = 0; it < 3; ++it) {
    // ---- stat: softmax stats per j (blocks 0..9), mz[j]=max, mz[10+j]=1/Z
    if (it > 0) {
      if (bid < 10) {
        const int j = bid;
        float m = -1e30f;
        for (int r = tid; r < R_; r += NTHR) m = fmaxf(m, bias[r * 10 + j]);
        stred[tid] = m;
        __syncthreads();
        for (int s = 128; s > 0; s >>= 1) {
          if (tid < s) stred[tid] = fmaxf(stred[tid], stred[tid + s]);
          __syncthreads();
        }
        m = stred[0];
        __syncthreads();
        float sum = 0.0f;
        for (int r = tid; r < R_; r += NTHR) sum += expf(bias[r * 10 + j] - m);
        stred[tid] = sum;
        __syncthreads();
        for (int s = 128; s > 0; s >>= 1) {
          if (tid < s) stred[tid] += stred[tid + s];
          __syncthreads();
        }
        if (tid == 0) {
          mz[j] = m;
          mz[10 + j] = 1.0f / stred[0];
        }
      }
      grid_bar(bar);
    }

    // ---- wcbuild: Wc = W * c in B-fragment order (184320 chunks)
#pragma unroll
    for (int q = 0; q < 3; ++q) {
      int idx = q * 65536 + gtid;
      if (idx < 184320) {
        int l = idx & 63;
        int rest = idx >> 6;
        int nb = rest % 10, kb = rest / 10;
        int r = kb * 4 + (l >> 4);
        int o = l & 15;
        const float4* wp =
            (const float4*)(W + (((size_t)r * 10 + nb) * 16 + o) * 8);
        float4 a = wp[0], b = wp[1];
        float cs = 1.0f;
        if (it > 0) cs = expf(bias[r * 10 + nb] - mz[nb]) * mz[10 + nb];
        bf16x8 pk;
        pk[0] = f2bf(a.x * cs); pk[1] = f2bf(a.y * cs);
        pk[2] = f2bf(a.z * cs); pk[3] = f2bf(a.w * cs);
        pk[4] = f2bf(b.x * cs); pk[5] = f2bf(b.y * cs);
        pk[6] = f2bf(b.z * cs); pk[7] = f2bf(b.w * cs);
        ((bf16x8*)wcf)[idx] = pk;
      }
    }
    grid_bar(bar);

    // ---- s-GEMM: 1024 wave-units (m16 in [0,32), ks-split in [0,32))
    {
      const int m16 = (bid & 7) * 4 + w;
      const int ks0 = (bid >> 3) * SPK_;
      f32x4 acc[10] = {};
      const bf16x8* ap =
          (const bf16x8*)xaf + ((size_t)m16 * 288 + ks0) * 64 + lane;
      const bf16x8* bp = (const bf16x8*)wcf + ((size_t)ks0 * 640 + lane);
      for (int st = 0; st < SPK_; ++st) {
        bf16x8 af = ap[0];
        ap += 64;
#pragma unroll
        for (int nb = 0; nb < 10; ++nb)
          acc[nb] = __builtin_amdgcn_mfma_f32_16x16x32_bf16(af, bp[nb * 64],
                                                            acc[nb], 0, 0, 0);
        bp += 640;
      }
      const float scale = (it == 0) ? (1.0f / 1152.0f) : 1.0f;
      float* pp = part + (size_t)(bid >> 3) * (B_ * JO_) +
                  (size_t)(m16 * 16 + (lane >> 4) * 4) * JO_ + (lane & 15);
#pragma unroll
      for (int nb = 0; nb < 10; ++nb)
#pragma unroll
        for (int q = 0; q < 4; ++q)
          pp[q * JO_ + nb * 16] = acc[nb][q] * scale;
    }
    grid_bar(bar);

    // ---- squash: reduce 32 k-planes + squash; tiles = (kb,nb), blocks 0..159
    if (bid < 160) {
      const int kb = bid / 10, nb = bid - (bid / 10) * 10;
      const int col = tid & 15;
      float val[2];
#pragma unroll
      for (int h = 0; h < 2; ++h) {
        int bl = (tid >> 4) + h * 16;
        const float* pe =
            part + (size_t)(kb * 32 + bl) * JO_ + nb * 16 + col;
        float pv[KS_];
#pragma unroll
        for (int ks = 0; ks < KS_; ++ks) pv[ks] = pe[(size_t)ks * (B_ * JO_)];
        float s = 0.0f;
#pragma unroll
        for (int ks = 0; ks < KS_; ++ks) s += pv[ks];
        val[h] = s * fabsf(s) / (1.0f + s * s);
      }
      if (it == 2) {
#pragma unroll
        for (int h = 0; h < 2; ++h) {
          int bl = (tid >> 4) + h * 16;
          out[(size_t)(kb * 32 + bl) * JO_ + nb * 16 + col] = val[h];
        }
      } else {
#pragma unroll
        for (int h = 0; h < 2; ++h) vsm[((tid >> 4) + h * 16) * 17 + col] = val[h];
        __syncthreads();
        if (tid < 64) {
          bf16x8 pk;
#pragma unroll
          for (int t = 0; t < 8; ++t)
            pk[t] = f2bf(vsm[((tid >> 4) * 8 + t) * 17 + (tid & 15)]);
          ((bf16x8*)vfrag)[(size_t)bid * 64 + tid] = pk;
        }
        __syncthreads();  // vsm aliases agree LDS; keep block-local ordering
      }
    }
    if (it == 2) break;  // done: out written
    grid_bar(bar);

    // ---- agree: per r-pair M = x_r^T @ v, then bias += (1/B) sum W*M
    for (int rp = bid; rp < 576; rp += NBLK) {
      const int r0 = rp * 2;
      f32x4 acc[10] = {};
      const bf16x8* ap =
          (const bf16x8*)xtf + ((size_t)rp * 16 + w * 4) * 64 + lane;
      const bf16x8* bp = (const bf16x8*)vfrag + (size_t)(w * 4) * 640 + lane;
#pragma unroll
      for (int ks = 0; ks < 4; ++ks) {
        bf16x8 af = ap[0];
        ap += 64;
#pragma unroll
        for (int nb = 0; nb < 10; ++nb)
          acc[nb] = __builtin_amdgcn_mfma_f32_16x16x32_bf16(af, bp[nb * 64],
                                                            acc[nb], 0, 0, 0);
        bp += 640;
      }
      __syncthreads();  // protect previous unit's Msm/red reads
      {
        int colc = lane & 15, rbase = (lane >> 4) * 4;
#pragma unroll
        for (int nb = 0; nb < 10; ++nb)
#pragma unroll
          for (int q = 0; q < 4; ++q)
            Msm[(w * 16 + rbase + q) * 176 + nb * 16 + colc] = acc[nb][q];
      }
      __syncthreads();
      for (int idx = tid; idx < 320; idx += NTHR) {
        int rr = idx / 160, jo = idx - rr * 160;
        int j = jo >> 4, o = jo & 15;
        float p = 0.0f;
        const float* wp = W + (((size_t)(r0 + rr) * 10 + j) * 16 + o) * 8;
#pragma unroll
        for (int i = 0; i < 8; ++i) {
          float m = Msm[(0 * 16 + rr * 8 + i) * 176 + jo] +
                    Msm[(1 * 16 + rr * 8 + i) * 176 + jo] +
                    Msm[(2 * 16 + rr * 8 + i) * 176 + jo] +
                    Msm[(3 * 16 + rr * 8 + i) * 176 + jo];
          p += wp[i] * m;
        }
        agred[idx] = p;
      }
      __syncthreads();
      if (tid < 20) {
        int rr = tid / 10, j = tid - rr * 10;
        float s = 0.0f;
#pragma unroll
        for (int o = 0; o < 16; ++o) s += agred[rr * 160 + j * 16 + o];
        bias[(r0 + rr) * 10 + j] += s * (1.0f / 512.0f);
      }
    }
    grid_bar(bar);
  }
}

extern "C" void kernel_launch(void* const* d_in, const int* in_sizes, int n_in,
                              void* d_out, int out_size, void* d_ws,
                              size_t ws_size, hipStream_t stream) {
  const float* x = (const float*)d_in[0];  // [512,1152,8]
  const float* W = (const float*)d_in[1];  // [1152,10,16,8]
  float* out = (float*)d_out;              // [512][160]
  char* ws = (char*)d_ws;

  // layout (bytes):
  unsigned* bar  = (unsigned*)(ws);            // 2 u32 (pad to 256)
  float*    bias = (float*)(ws + 256);         // 46080
  float*    mz   = (float*)(ws + 46336);       // 80
  short*    vfrag= (short*)(ws + 46592);       // 163840
  short*    wcf  = (short*)(ws + 210944);      // 2949120
  short*    xaf  = (short*)(ws + 3160064);     // 9437184
  short*    xtf  = (short*)(ws + 12597248);    // 9437184
  float*    part = (float*)(ws + 22034432);    // 10485760 -> ends 32520192

  barinit_kernel<<<1, 64, 0, stream>>>(bar);
  digitcaps_kernel<<<NBLK, NTHR, 0, stream>>>(x, W, xaf, xtf, wcf, part,
                                              vfrag, bias, mz, out, bar);
}

// Round 8
// 360.094 us; speedup vs baseline: 2.1919x; 2.1919x over previous
//
#include <hip/hip_runtime.h>

// DigitCaps routing, single persistent kernel (+ tiny barrier-init kernel).
// B=512, R=1152, J=10, O=16, I=8, JO=160, K=R*I=9216.
// s[b,jo]    = sum_k x[b,k] * Wc[k,jo],  Wc[(r,i),(j,o)] = W[r,j,o,i]*c[r,j]
// v          = s*|s|/(1+s^2)
// bias[r,j] += (1/B) sum_{i,o} W[r,j,o,i] * M[(r,i),(j,o)],  M = x_r^T @ v
// c          = softmax_r(bias)
//
// r7 post-mortem: barrier cost ~60us each from (a) count/gen false sharing,
// (b) ACQUIRE poll per spin iteration, (c) 1 wave/SIMD occupancy. Fixed:
// padded barrier words, RELAXED spin + fence-on-exit, 512-thread blocks
// (2 waves/SIMD), stats computed redundantly per-block (11 barriers, not 13).
// All reductions fixed-order -> deterministic.

#define B_   512
#define R_   1152
#define JO_  160
#define K_   9216
#define KS_  32
#define SPK_ 9
#define NBLK 256
#define NTHR 512

typedef __attribute__((ext_vector_type(4))) float f32x4;
typedef __attribute__((ext_vector_type(8))) short bf16x8;

__device__ __forceinline__ short f2bf(float f) {
  unsigned int u = __float_as_uint(f);
  unsigned int r = (u + 0x7FFFu + ((u >> 16) & 1u)) >> 16;
  return (short)r;
}

__global__ void barinit_kernel(unsigned* __restrict__ bar) {
  if (threadIdx.x == 0) {
    bar[0] = 0u;    // arrive count
    bar[64] = 0u;   // generation (separate 256B line)
  }
}

// Sense-reversing generation barrier. count@bar[0], gen@bar[64] (padded).
// Arrive: release fence + RELAXED fetch_add. Wait: RELAXED polls + backoff,
// acquire fence once on exit.
__device__ __forceinline__ void grid_bar(unsigned* bar) {
  __syncthreads();
  if (threadIdx.x == 0) {
    __threadfence();  // release my block's prior writes
    unsigned g =
        __hip_atomic_load(bar + 64, __ATOMIC_RELAXED, __HIP_MEMORY_SCOPE_AGENT);
    unsigned a = __hip_atomic_fetch_add(bar, 1u, __ATOMIC_RELAXED,
                                        __HIP_MEMORY_SCOPE_AGENT);
    if (a == NBLK - 1) {
      __hip_atomic_store(bar, 0u, __ATOMIC_RELAXED, __HIP_MEMORY_SCOPE_AGENT);
      __hip_atomic_store(bar + 64, g + 1u, __ATOMIC_RELEASE,
                         __HIP_MEMORY_SCOPE_AGENT);
    } else {
      while (__hip_atomic_load(bar + 64, __ATOMIC_RELAXED,
                               __HIP_MEMORY_SCOPE_AGENT) == g)
        __builtin_amdgcn_s_sleep(2);
    }
    __threadfence();  // acquire everyone's writes
  }
  __syncthreads();
}

__global__ __launch_bounds__(NTHR, 2) void digitcaps_kernel(
    const float* __restrict__ x, const float* __restrict__ W,
    short* __restrict__ xaf, short* __restrict__ xtf,
    short* __restrict__ wcf, float* __restrict__ part,
    short* __restrict__ vfrag, float* __restrict__ bias,
    float* __restrict__ out, unsigned* __restrict__ bar) {
  __shared__ float Msm[4 * 16 * 176];  // 45056 B (agree); vsm aliases (squash)
  __shared__ float agred[320];
  __shared__ float mzs[20];
  float* vsm = Msm;

  const int tid = threadIdx.x;
  const int bid = blockIdx.x;
  const int gtid = bid * NTHR + tid;  // < 131072
  const int w = tid >> 6, lane = tid & 63;

  // ---- P0: build xaf (s-GEMM A-frags), xtf (agree A-frags), zero bias
  if (gtid < R_ * 10) bias[gtid] = 0.0f;
  for (int gid = gtid; gid < 589824; gid += NBLK * NTHR) {
    int l = gid & 63, f = gid >> 6;
    int ks = f % 288, m16 = f / 288;
    int row = m16 * 16 + (l & 15);
    int k0 = ks * 32 + (l >> 4) * 8;
    const float4* p = (const float4*)(x + (size_t)row * K_ + k0);
    float4 a = p[0], b = p[1];
    bf16x8 pk;
    pk[0] = f2bf(a.x); pk[1] = f2bf(a.y); pk[2] = f2bf(a.z); pk[3] = f2bf(a.w);
    pk[4] = f2bf(b.x); pk[5] = f2bf(b.y); pk[6] = f2bf(b.z); pk[7] = f2bf(b.w);
    ((bf16x8*)xaf)[gid] = pk;
  }
  for (int gid = gtid; gid < 589824; gid += NBLK * NTHR) {
    int l = gid & 63, f = gid >> 6;
    int kb = f & 15, rp = f >> 4;
    int b0 = kb * 32 + (l >> 4) * 8;
    const float* p = x + (size_t)b0 * K_ + rp * 16 + (l & 15);
    bf16x8 pk;
#pragma unroll
    for (int t = 0; t < 8; ++t) pk[t] = f2bf(p[(size_t)t * K_]);
    ((bf16x8*)xtf)[gid] = pk;
  }
  grid_bar(bar);

  for (int it = 0; it < 3; ++it) {
    // ---- stat (redundant per block): mzs[j]=max_r bias, mzs[10+j]=1/Z
    if (it > 0) {
      for (int j = w; j < 10; j += 8) {
        float m = -1e30f;
        for (int r = lane; r < R_; r += 64) m = fmaxf(m, bias[r * 10 + j]);
#pragma unroll
        for (int d = 32; d; d >>= 1) m = fmaxf(m, __shfl_xor(m, d));
        float sum = 0.0f;
        for (int r = lane; r < R_; r += 64) sum += expf(bias[r * 10 + j] - m);
#pragma unroll
        for (int d = 32; d; d >>= 1) sum += __shfl_xor(sum, d);
        if (lane == 0) {
          mzs[j] = m;
          mzs[10 + j] = 1.0f / sum;
        }
      }
      __syncthreads();
    }

    // ---- wcbuild: Wc = W * c in B-fragment order (184320 16B chunks)
    for (int idx = gtid; idx < 184320; idx += NBLK * NTHR) {
      int l = idx & 63;
      int rest = idx >> 6;
      int nb = rest % 10, kb = rest / 10;
      int r = kb * 4 + (l >> 4);
      int o = l & 15;
      const float4* wp =
          (const float4*)(W + (((size_t)r * 10 + nb) * 16 + o) * 8);
      float4 a = wp[0], b = wp[1];
      float cs = 1.0f;
      if (it > 0) cs = expf(bias[r * 10 + nb] - mzs[nb]) * mzs[10 + nb];
      bf16x8 pk;
      pk[0] = f2bf(a.x * cs); pk[1] = f2bf(a.y * cs);
      pk[2] = f2bf(a.z * cs); pk[3] = f2bf(a.w * cs);
      pk[4] = f2bf(b.x * cs); pk[5] = f2bf(b.y * cs);
      pk[6] = f2bf(b.z * cs); pk[7] = f2bf(b.w * cs);
      ((bf16x8*)wcf)[idx] = pk;
    }
    grid_bar(bar);

    // ---- s-GEMM: waves 0-3 (one per SIMD): unit (m16, ks-split)
    if (w < 4) {
      const int m16 = (bid & 7) * 4 + w;
      const int ks0 = (bid >> 3) * SPK_;
      f32x4 acc[10] = {};
      const bf16x8* ap =
          (const bf16x8*)xaf + ((size_t)m16 * 288 + ks0) * 64 + lane;
      const bf16x8* bp = (const bf16x8*)wcf + ((size_t)ks0 * 640 + lane);
      for (int st = 0; st < SPK_; ++st) {
        bf16x8 af = ap[0];
        ap += 64;
#pragma unroll
        for (int nb = 0; nb < 10; ++nb)
          acc[nb] = __builtin_amdgcn_mfma_f32_16x16x32_bf16(af, bp[nb * 64],
                                                            acc[nb], 0, 0, 0);
        bp += 640;
      }
      const float scale = (it == 0) ? (1.0f / 1152.0f) : 1.0f;
      float* pp = part + (size_t)(bid >> 3) * (B_ * JO_) +
                  (size_t)(m16 * 16 + (lane >> 4) * 4) * JO_ + (lane & 15);
#pragma unroll
      for (int nb = 0; nb < 10; ++nb)
#pragma unroll
        for (int q = 0; q < 4; ++q)
          pp[q * JO_ + nb * 16] = acc[nb][q] * scale;
    }
    grid_bar(bar);

    // ---- squash: reduce 32 k-planes + squash; tile (kb,nb) = blocks 0..159
    if (bid < 160) {
      const int kb = bid / 10, nb = bid - (bid / 10) * 10;
      const int bl = tid >> 4, col = tid & 15;  // 32 x 16 = 512 threads
      const float* pe = part + (size_t)(kb * 32 + bl) * JO_ + nb * 16 + col;
      float pv[KS_];
#pragma unroll
      for (int ks = 0; ks < KS_; ++ks) pv[ks] = pe[(size_t)ks * (B_ * JO_)];
      float s = 0.0f;
#pragma unroll
      for (int ks = 0; ks < KS_; ++ks) s += pv[ks];
      float val = s * fabsf(s) / (1.0f + s * s);
      if (it == 2) {
        out[(size_t)(kb * 32 + bl) * JO_ + nb * 16 + col] = val;
      } else {
        vsm[bl * 17 + col] = val;
        __syncthreads();
        if (tid < 64) {
          bf16x8 pk;
#pragma unroll
          for (int t = 0; t < 8; ++t)
            pk[t] = f2bf(vsm[((tid >> 4) * 8 + t) * 17 + (tid & 15)]);
          ((bf16x8*)vfrag)[(size_t)bid * 64 + tid] = pk;
        }
        __syncthreads();  // vsm aliases Msm
      }
    }
    if (it == 2) break;
    grid_bar(bar);

    // ---- agree: waves 0-3; per r-pair M = x_r^T @ v, bias += (1/B) sum W*M
    for (int rp = bid; rp < 576; rp += NBLK) {
      const int r0 = rp * 2;
      f32x4 acc[10] = {};
      if (w < 4) {
        const bf16x8* ap =
            (const bf16x8*)xtf + ((size_t)rp * 16 + w * 4) * 64 + lane;
        const bf16x8* bp = (const bf16x8*)vfrag + (size_t)(w * 4) * 640 + lane;
#pragma unroll
        for (int ks = 0; ks < 4; ++ks) {
          bf16x8 af = ap[0];
          ap += 64;
#pragma unroll
          for (int nb = 0; nb < 10; ++nb)
            acc[nb] = __builtin_amdgcn_mfma_f32_16x16x32_bf16(af, bp[nb * 64],
                                                              acc[nb], 0, 0, 0);
          bp += 640;
        }
      }
      __syncthreads();  // protect previous unit's Msm/agred reads
      if (w < 4) {
        int colc = lane & 15, rbase = (lane >> 4) * 4;
#pragma unroll
        for (int nb = 0; nb < 10; ++nb)
#pragma unroll
          for (int q = 0; q < 4; ++q)
            Msm[(w * 16 + rbase + q) * 176 + nb * 16 + colc] = acc[nb][q];
      }
      __syncthreads();
      if (tid < 320) {
        int rr = tid / 160, jo = tid - rr * 160;
        int j = jo >> 4, o = jo & 15;
        float p = 0.0f;
        const float* wp = W + (((size_t)(r0 + rr) * 10 + j) * 16 + o) * 8;
#pragma unroll
        for (int i = 0; i < 8; ++i) {
          float m = Msm[(0 * 16 + rr * 8 + i) * 176 + jo] +
                    Msm[(1 * 16 + rr * 8 + i) * 176 + jo] +
                    Msm[(2 * 16 + rr * 8 + i) * 176 + jo] +
                    Msm[(3 * 16 + rr * 8 + i) * 176 + jo];
          p += wp[i] * m;
        }
        agred[tid] = p;
      }
      __syncthreads();
      if (tid < 20) {
        int rr = tid / 10, j = tid - rr * 10;
        float s = 0.0f;
#pragma unroll
        for (int o = 0; o < 16; ++o) s += agred[rr * 160 + j * 16 + o];
        bias[(r0 + rr) * 10 + j] += s * (1.0f / 512.0f);
      }
    }
    grid_bar(bar);
  }
}

extern "C" void kernel_launch(void* const* d_in, const int* in_sizes, int n_in,
                              void* d_out, int out_size, void* d_ws,
                              size_t ws_size, hipStream_t stream) {
  const float* x = (const float*)d_in[0];  // [512,1152,8]
  const float* W = (const float*)d_in[1];  // [1152,10,16,8]
  float* out = (float*)d_out;              // [512][160]
  char* ws = (char*)d_ws;

  // layout (bytes):
  unsigned* bar  = (unsigned*)(ws);            // 2 padded u32 (512 B)
  float*    bias = (float*)(ws + 512);         // 46080
  short*    vfrag= (short*)(ws + 46592);       // 163840
  short*    wcf  = (short*)(ws + 210944);      // 2949120
  short*    xaf  = (short*)(ws + 3160064);     // 9437184
  short*    xtf  = (short*)(ws + 12597248);    // 9437184
  float*    part = (float*)(ws + 22034432);    // 10485760 -> ends 32520192

  barinit_kernel<<<1, 64, 0, stream>>>(bar);
  digitcaps_kernel<<<NBLK, NTHR, 0, stream>>>(x, W, xaf, xtf, wcf, part,
                                              vfrag, bias, out, bar);
}

// Round 9
// 114.890 us; speedup vs baseline: 6.8701x; 3.1342x over previous
//
#include <hip/hip_runtime.h>

// DigitCaps routing via MFMA, u_hat never materialized. Multi-kernel (the
// persistent/grid-barrier variants r7/r8 proved strictly worse: a software
// barrier over 8 non-coherent XCDs costs >= 27us vs ~2us dispatch boundary).
// B=512, R=1152, J=10, O=16, I=8, JO=160, K=R*I=9216.
// s[b,jo]    = sum_k x[b,k] * Wc[k,jo],  Wc[(r,i),(j,o)] = W[r,j,o,i]*c[r,j]
// v          = s*|s|/(1+s^2)
// bias[r,j] += (1/B) sum_{i,o} W[r,j,o,i] * M[(r,i),(j,o)],  M = x_r^T @ v
// c          = softmax_r(bias)
//
// 11 dispatches: prep (xaf+xtf+bias0+wcf_it0) | 3x{ [wcstat] sgemm squash }
// | 2x agree, with wcstat folding softmax stats in-block (redundant, fixed
// order -> deterministic).

#define B_   512
#define R_   1152
#define JO_  160
#define K_   9216
#define KS_  32
#define SPK_ 9

typedef __attribute__((ext_vector_type(4))) float f32x4;
typedef __attribute__((ext_vector_type(8))) short bf16x8;

__device__ __forceinline__ short f2bf(float f) {
  unsigned int u = __float_as_uint(f);
  unsigned int r = (u + 0x7FFFu + ((u >> 16) & 1u)) >> 16;
  return (short)r;
}

// ---- prep: xaf (s-GEMM A-frags), xtf (agree A-frags), bias=0, wcf (it0, c=1)
// grid 2304 x 256 (589824 threads, one fragment each per pass).
__global__ __launch_bounds__(256) void prep_kernel(
    const float* __restrict__ x, const float* __restrict__ W,
    short* __restrict__ xaf, short* __restrict__ xtf,
    short* __restrict__ wcf, float* __restrict__ bias) {
  int gid = blockIdx.x * 256 + threadIdx.x;  // < 589824
  if (gid < R_ * 10) bias[gid] = 0.0f;
  {  // xaf: frag f = m16*288+ks; lane l: row m16*16+(l&15), k=ks*32+(l>>4)*8+t
    int l = gid & 63, f = gid >> 6;
    int ks = f % 288, m16 = f / 288;
    int row = m16 * 16 + (l & 15);
    int k0 = ks * 32 + (l >> 4) * 8;
    const float4* p = (const float4*)(x + (size_t)row * K_ + k0);
    float4 a = p[0], b = p[1];
    bf16x8 pk;
    pk[0] = f2bf(a.x); pk[1] = f2bf(a.y); pk[2] = f2bf(a.z); pk[3] = f2bf(a.w);
    pk[4] = f2bf(b.x); pk[5] = f2bf(b.y); pk[6] = f2bf(b.z); pk[7] = f2bf(b.w);
    ((bf16x8*)xaf)[gid] = pk;
  }
  {  // xtf: frag f = rp*16+kb; lane l: row (l&15) of r-pair rp, k=b
    int l = gid & 63, f = gid >> 6;
    int kb = f & 15, rp = f >> 4;
    int b0 = kb * 32 + (l >> 4) * 8;
    const float* p = x + (size_t)b0 * K_ + rp * 16 + (l & 15);
    bf16x8 pk;
#pragma unroll
    for (int t = 0; t < 8; ++t) pk[t] = f2bf(p[(size_t)t * K_]);
    ((bf16x8*)xtf)[gid] = pk;
  }
  if (gid < 184320) {  // wcf iter0: unscaled W in B-frag order
    int l = gid & 63;
    int rest = gid >> 6;
    int nb = rest % 10, kb = rest / 10;
    int r = kb * 4 + (l >> 4);
    int o = l & 15;
    const float4* wp = (const float4*)(W + (((size_t)r * 10 + nb) * 16 + o) * 8);
    float4 a = wp[0], b = wp[1];
    bf16x8 pk;
    pk[0] = f2bf(a.x); pk[1] = f2bf(a.y); pk[2] = f2bf(a.z); pk[3] = f2bf(a.w);
    pk[4] = f2bf(b.x); pk[5] = f2bf(b.y); pk[6] = f2bf(b.z); pk[7] = f2bf(b.w);
    ((bf16x8*)wcf)[gid] = pk;
  }
}

// ---- wcstat: in-block softmax stats (redundant, fixed order) + Wc build.
// grid 720 x 256 (one chunk per thread).
__global__ __launch_bounds__(256) void wcstat_kernel(
    const float* __restrict__ W, const float* __restrict__ bias,
    short* __restrict__ wcf) {
  __shared__ float mzs[20];
  const int tid = threadIdx.x;
  const int w = tid >> 6, lane = tid & 63;
  for (int j = w; j < 10; j += 4) {
    float m = -1e30f;
    for (int r = lane; r < R_; r += 64) m = fmaxf(m, bias[r * 10 + j]);
#pragma unroll
    for (int d = 32; d; d >>= 1) m = fmaxf(m, __shfl_xor(m, d));
    float sum = 0.0f;
    for (int r = lane; r < R_; r += 64) sum += expf(bias[r * 10 + j] - m);
#pragma unroll
    for (int d = 32; d; d >>= 1) sum += __shfl_xor(sum, d);
    if (lane == 0) {
      mzs[j] = m;
      mzs[10 + j] = 1.0f / sum;
    }
  }
  __syncthreads();
  int idx = blockIdx.x * 256 + tid;  // < 184320
  int l = idx & 63;
  int rest = idx >> 6;
  int nb = rest % 10, kb = rest / 10;
  int r = kb * 4 + (l >> 4);
  int o = l & 15;
  const float4* wp = (const float4*)(W + (((size_t)r * 10 + nb) * 16 + o) * 8);
  float4 a = wp[0], b = wp[1];
  float cs = expf(bias[r * 10 + nb] - mzs[nb]) * mzs[10 + nb];
  bf16x8 pk;
  pk[0] = f2bf(a.x * cs); pk[1] = f2bf(a.y * cs);
  pk[2] = f2bf(a.z * cs); pk[3] = f2bf(a.w * cs);
  pk[4] = f2bf(b.x * cs); pk[5] = f2bf(b.y * cs);
  pk[6] = f2bf(b.z * cs); pk[7] = f2bf(b.w * cs);
  ((bf16x8*)wcf)[idx] = pk;
}

// ---- s-GEMM: grid (8, 32), 4 waves; wave = one m16-tile x 160, 9 k-steps.
// Operands fragment-direct from global (no LDS).
template <bool SCALE>
__global__ __launch_bounds__(256) void sgemm_kernel(
    const short* __restrict__ xaf, const short* __restrict__ wcf,
    float* __restrict__ part) {
  const int tid = threadIdx.x;
  const int w = tid >> 6, lane = tid & 63;
  const int m16 = blockIdx.x * 4 + w;
  const int ks0 = blockIdx.y * SPK_;

  f32x4 acc[10] = {};
  const bf16x8* ap = (const bf16x8*)xaf + ((size_t)m16 * 288 + ks0) * 64 + lane;
  const bf16x8* bp = (const bf16x8*)wcf + ((size_t)ks0 * 640 + lane);
  for (int st = 0; st < SPK_; ++st) {
    bf16x8 af = ap[0];
    ap += 64;
#pragma unroll
    for (int nb = 0; nb < 10; ++nb)
      acc[nb] = __builtin_amdgcn_mfma_f32_16x16x32_bf16(af, bp[nb * 64],
                                                        acc[nb], 0, 0, 0);
    bp += 640;
  }
  // C/D: col=lane&15, row=(lane>>4)*4+q
  const float scale = SCALE ? (1.0f / 1152.0f) : 1.0f;
  float* pp = part + (size_t)blockIdx.y * (B_ * JO_) +
              (size_t)(m16 * 16 + (lane >> 4) * 4) * JO_ + (lane & 15);
#pragma unroll
  for (int nb = 0; nb < 10; ++nb)
#pragma unroll
    for (int q = 0; q < 4; ++q)
      pp[q * JO_ + nb * 16] = acc[nb][q] * scale;
}

// ---- squash: reduce 32 k-planes + squash; grid 160 (one (kb,nb) 32x16 tile),
// block 512, 1 element/thread, explicit pv[32] for back-to-back loads.
__global__ __launch_bounds__(512) void squash_kernel(
    const float* __restrict__ part, short* __restrict__ vfrag,
    float* __restrict__ out) {
  __shared__ float vsm[32][17];
  const int tid = threadIdx.x;  // 0..511
  const int kb = blockIdx.x / 10, nb = blockIdx.x - (blockIdx.x / 10) * 10;
  const int bl = tid >> 4, col = tid & 15;
  const float* pe = part + (size_t)(kb * 32 + bl) * JO_ + nb * 16 + col;
  float pv[KS_];
#pragma unroll
  for (int ks = 0; ks < KS_; ++ks) pv[ks] = pe[(size_t)ks * (B_ * JO_)];
  float s = 0.0f;
#pragma unroll
  for (int ks = 0; ks < KS_; ++ks) s += pv[ks];
  float val = s * fabsf(s) / (1.0f + s * s);
  if (out) out[(size_t)(kb * 32 + bl) * JO_ + nb * 16 + col] = val;
  if (vfrag) {
    vsm[bl][col] = val;
    __syncthreads();
    if (tid < 64) {
      bf16x8 pk;
#pragma unroll
      for (int t = 0; t < 8; ++t)
        pk[t] = f2bf(vsm[(tid >> 4) * 8 + t][tid & 15]);
      ((bf16x8*)vfrag)[(size_t)blockIdx.x * 64 + tid] = pk;
    }
  }
}

// ---- agree: per r-pair M[16x160] = x_r^T @ v (K=B=512, 4 waves x 128),
// then bias[r,j] += (1/B) sum_{i,o} W*M, fused. grid 576 x 256.
__global__ __launch_bounds__(256) void agree_kernel(
    const short* __restrict__ xtf, const float* __restrict__ W,
    const short* __restrict__ vfrag, float* __restrict__ bias) {
  __shared__ float Msm[4][16][176];
  __shared__ float red[320];
  const int tid = threadIdx.x;
  const int w = tid >> 6, lane = tid & 63;
  const int rp = blockIdx.x;
  const int r0 = rp * 2;

  f32x4 acc[10] = {};
  const bf16x8* ap = (const bf16x8*)xtf + ((size_t)rp * 16 + w * 4) * 64 + lane;
  const bf16x8* bp = (const bf16x8*)vfrag + ((size_t)(w * 4) * 640 + lane);
#pragma unroll
  for (int ks = 0; ks < 4; ++ks) {
    bf16x8 af = ap[0];
    ap += 64;
#pragma unroll
    for (int nb = 0; nb < 10; ++nb)
      acc[nb] = __builtin_amdgcn_mfma_f32_16x16x32_bf16(af, bp[nb * 64],
                                                        acc[nb], 0, 0, 0);
    bp += 640;
  }
  {
    int colc = lane & 15, rbase = (lane >> 4) * 4;
#pragma unroll
    for (int nb = 0; nb < 10; ++nb)
#pragma unroll
      for (int q = 0; q < 4; ++q)
        Msm[w][rbase + q][nb * 16 + colc] = acc[nb][q];
  }
  __syncthreads();
  for (int idx = tid; idx < 320; idx += 256) {
    int rr = idx / 160, jo = idx - rr * 160;
    int j = jo >> 4, o = jo & 15;
    float p = 0.0f;
    const float* wp = W + (((size_t)(r0 + rr) * 10 + j) * 16 + o) * 8;
#pragma unroll
    for (int i = 0; i < 8; ++i) {
      float m = Msm[0][rr * 8 + i][jo] + Msm[1][rr * 8 + i][jo] +
                Msm[2][rr * 8 + i][jo] + Msm[3][rr * 8 + i][jo];
      p += wp[i] * m;
    }
    red[idx] = p;
  }
  __syncthreads();
  if (tid < 20) {
    int rr = tid / 10, j = tid - rr * 10;
    float s = 0.0f;
#pragma unroll
    for (int o = 0; o < 16; ++o) s += red[rr * 160 + j * 16 + o];
    bias[(r0 + rr) * 10 + j] += s * (1.0f / 512.0f);
  }
}

extern "C" void kernel_launch(void* const* d_in, const int* in_sizes, int n_in,
                              void* d_out, int out_size, void* d_ws,
                              size_t ws_size, hipStream_t stream) {
  const float* x = (const float*)d_in[0];  // [512,1152,8]
  const float* W = (const float*)d_in[1];  // [1152,10,16,8]
  float* out = (float*)d_out;              // [512][160]
  char* ws = (char*)d_ws;

  // layout (bytes):
  float* bias  = (float*)(ws);             // 46080
  short* vfrag = (short*)(ws + 46080);     // 163840
  short* wcf   = (short*)(ws + 209920);    // 2949120
  short* xaf   = (short*)(ws + 3159040);   // 9437184
  short* xtf   = (short*)(ws + 12596224);  // 9437184
  float* part  = (float*)(ws + 22033408);  // 10485760 -> ends 32519168

  prep_kernel<<<2304, 256, 0, stream>>>(x, W, xaf, xtf, wcf, bias);

  // iter 0 (c uniform, folded as 1/1152 epilogue scale)
  sgemm_kernel<true><<<dim3(8, KS_), 256, 0, stream>>>(xaf, wcf, part);
  squash_kernel<<<160, 512, 0, stream>>>(part, vfrag, nullptr);
  agree_kernel<<<576, 256, 0, stream>>>(xtf, W, vfrag, bias);
  // iter 1
  wcstat_kernel<<<720, 256, 0, stream>>>(W, bias, wcf);
  sgemm_kernel<false><<<dim3(8, KS_), 256, 0, stream>>>(xaf, wcf, part);
  squash_kernel<<<160, 512, 0, stream>>>(part, vfrag, nullptr);
  agree_kernel<<<576, 256, 0, stream>>>(xtf, W, vfrag, bias);
  // iter 2
  wcstat_kernel<<<720, 256, 0, stream>>>(W, bias, wcf);
  sgemm_kernel<false><<<dim3(8, KS_), 256, 0, stream>>>(xaf, wcf, part);
  squash_kernel<<<160, 512, 0, stream>>>(part, nullptr, out);
}

// Round 10
// 98.750 us; speedup vs baseline: 7.9930x; 1.1634x over previous
//
#include <hip/hip_runtime.h>

// DigitCaps routing via MFMA, u_hat never materialized. Multi-kernel, r4
// skeleton (merging aux kernels measurably regressed; persistent-kernel
// grid barriers cost >=27us vs ~2us dispatch boundaries - r7/r8).
// B=512, R=1152, J=10, O=16, I=8, JO=160, K=R*I=9216.
// s[b,jo]    = sum_k x[b,k] * Wc[k,jo],  Wc[(r,i),(j,o)] = W[r,j,o,i]*c[r,j]
// v          = s*|s|/(1+s^2)
// bias[r,j] += (1/B) sum_{i,o} W[r,j,o,i] * M[(r,i),(j,o)],  M = x_r^T @ v
// c          = softmax_r(bias)
//
// r9 fix: squash was ~28us/call - part was 10.5MB of cross-XCD 64B-line
// scatter. Now: KS=8 (sgemm blocks reduce 4 waves' k-partials in-block via
// LDS, fixed order) + tile-contiguous part[ks][nb][kb][32][16] so squash
// reads are contiguous 2KB runs. part: 2.6MB.

#define B_   512
#define R_   1152
#define JO_  160
#define K_   9216
#define KS_  8     // part planes
#define WPK_ 9     // k-steps per wave (4 waves * 9 = 36 per plane)

typedef __attribute__((ext_vector_type(4))) float f32x4;
typedef __attribute__((ext_vector_type(8))) short bf16x8;

__device__ __forceinline__ short f2bf(float f) {
  unsigned int u = __float_as_uint(f);
  unsigned int r = (u + 0x7FFFu + ((u >> 16) & 1u)) >> 16;
  return (short)r;
}

__global__ __launch_bounds__(256) void init_kernel(float* __restrict__ bias,
                                                   float* __restrict__ c) {
  int idx = blockIdx.x * 256 + threadIdx.x;
  if (idx < R_ * 10) {
    bias[idx] = 0.0f;
    c[idx] = 1.0f / (float)R_;
  }
}

// ---- one-time: x -> A-fragment order for the s-GEMM.
// frag f = m16*288+ks; lane l: row m16*16+(l&15), k = ks*32+(l>>4)*8+t.
__global__ __launch_bounds__(256) void xafbuild_kernel(
    const float* __restrict__ x, short* __restrict__ xaf) {
  int gid = blockIdx.x * 256 + threadIdx.x;  // < 589824
  int lane = gid & 63, f = gid >> 6;
  int ks = f % 288, m16 = f / 288;
  int row = m16 * 16 + (lane & 15);
  int k0 = ks * 32 + (lane >> 4) * 8;
  const float4* p = (const float4*)(x + (size_t)row * K_ + k0);
  float4 a = p[0], b = p[1];
  bf16x8 pk;
  pk[0] = f2bf(a.x); pk[1] = f2bf(a.y); pk[2] = f2bf(a.z); pk[3] = f2bf(a.w);
  pk[4] = f2bf(b.x); pk[5] = f2bf(b.y); pk[6] = f2bf(b.z); pk[7] = f2bf(b.w);
  ((bf16x8*)xaf)[gid] = pk;
}

// ---- one-time: x^T -> A-fragment order for agreement.
// frag f = rp*16+kb; lane l: row (l&15) of r-pair rp, k = b = kb*32+(l>>4)*8+t.
__global__ __launch_bounds__(256) void xtfbuild_kernel(
    const float* __restrict__ x, short* __restrict__ xtf) {
  int gid = blockIdx.x * 256 + threadIdx.x;  // < 589824
  int lane = gid & 63, f = gid >> 6;
  int kb = f & 15, rp = f >> 4;
  int b0 = kb * 32 + (lane >> 4) * 8;
  const float* p = x + (size_t)b0 * K_ + rp * 16 + (lane & 15);
  bf16x8 pk;
#pragma unroll
  for (int t = 0; t < 8; ++t) pk[t] = f2bf(p[(size_t)t * K_]);
  ((bf16x8*)xtf)[gid] = pk;
}

// Build Wc in B-fragment order. frag (kb*10+nb), lane l: k=kb*32+(l>>4)*8+t,
// n=nb*16+(l&15). grid 720.
__global__ __launch_bounds__(256) void wcbuild_kernel(
    const float* __restrict__ W, const float* __restrict__ c,
    short* __restrict__ wcf) {
  int idx = blockIdx.x * 256 + threadIdx.x;  // < 184320
  int lane = idx & 63;
  int rest = idx >> 6;
  int nb = rest % 10, kb = rest / 10;
  int r = kb * 4 + (lane >> 4);
  int o = lane & 15;
  const float4* wp = (const float4*)(W + (((size_t)r * 10 + nb) * 16 + o) * 8);
  float4 a = wp[0], b = wp[1];
  float cs = c[r * 10 + nb];
  bf16x8 pk;
  pk[0] = f2bf(a.x * cs); pk[1] = f2bf(a.y * cs);
  pk[2] = f2bf(a.z * cs); pk[3] = f2bf(a.w * cs);
  pk[4] = f2bf(b.x * cs); pk[5] = f2bf(b.y * cs);
  pk[6] = f2bf(b.z * cs); pk[7] = f2bf(b.w * cs);
  ((bf16x8*)wcf)[idx] = pk;
}

// ---- s-GEMM: grid (32 m16-tiles, 8 k-groups), 4 waves split 36 k-steps,
// in-block LDS reduce (fixed order), write ONE plane in tiled layout
// part[ks][nb][kb][32][16].
__global__ __launch_bounds__(256) void sgemm_kernel(
    const short* __restrict__ xaf, const short* __restrict__ wcf,
    float* __restrict__ part) {
  __shared__ float sm[4 * 64 * 41];  // 41984 B
  const int tid = threadIdx.x;
  const int w = tid >> 6, lane = tid & 63;
  const int m16 = blockIdx.x;
  const int ks8 = blockIdx.y;
  const int ks0 = ks8 * 36 + w * WPK_;

  f32x4 acc[10] = {};
  const bf16x8* ap = (const bf16x8*)xaf + ((size_t)m16 * 288 + ks0) * 64 + lane;
  const bf16x8* bp = (const bf16x8*)wcf + ((size_t)ks0 * 640 + lane);
  for (int st = 0; st < WPK_; ++st) {
    bf16x8 af = ap[0];
    ap += 64;
#pragma unroll
    for (int nb = 0; nb < 10; ++nb)
      acc[nb] = __builtin_amdgcn_mfma_f32_16x16x32_bf16(af, bp[nb * 64],
                                                        acc[nb], 0, 0, 0);
    bp += 640;
  }
  {
    float* dst = sm + (size_t)(w * 64 + lane) * 41;
#pragma unroll
    for (int nb = 0; nb < 10; ++nb)
#pragma unroll
      for (int q = 0; q < 4; ++q) dst[nb * 4 + q] = acc[nb][q];
  }
  __syncthreads();
  // thread owns 10 slots of the 64x40 tile: lane_r = tid/4, c0 = (tid%4)*10
  const int lane_r = tid >> 2;
  const int c0 = (tid & 3) * 10;
  const int kb = m16 >> 1;
#pragma unroll
  for (int u = 0; u < 10; ++u) {
    int cc = c0 + u;
    float s = sm[(0 * 64 + lane_r) * 41 + cc] +
              sm[(1 * 64 + lane_r) * 41 + cc] +
              sm[(2 * 64 + lane_r) * 41 + cc] +
              sm[(3 * 64 + lane_r) * 41 + cc];
    int nb = cc >> 2, q = cc & 3;
    int bl = (m16 & 1) * 16 + (lane_r >> 4) * 4 + q;
    int colc = lane_r & 15;
    part[((((size_t)ks8 * 10 + nb) * 16 + kb) * 32 + bl) * 16 + colc] = s;
  }
}

// ---- squash: reduce 8 tiled planes + squash; grid 160 (one (kb,nb) tile),
// block 512, 1 element/thread; per-plane reads are contiguous 2KB runs.
__global__ __launch_bounds__(512) void squash_kernel(
    const float* __restrict__ part, short* __restrict__ vfrag,
    float* __restrict__ out) {
  __shared__ float vsm[32][17];
  const int tid = threadIdx.x;  // 0..511
  const int kb = blockIdx.x / 10, nb = blockIdx.x - (blockIdx.x / 10) * 10;
  const int bl = tid >> 4, col = tid & 15;
  const float* pe = part + (((size_t)nb * 16 + kb) * 32 + bl) * 16 + col;
  float pv[KS_];
#pragma unroll
  for (int ks = 0; ks < KS_; ++ks) pv[ks] = pe[(size_t)ks * (B_ * JO_)];
  float s = 0.0f;
#pragma unroll
  for (int ks = 0; ks < KS_; ++ks) s += pv[ks];
  float val = s * fabsf(s) / (1.0f + s * s);
  if (out) out[(size_t)(kb * 32 + bl) * JO_ + nb * 16 + col] = val;
  if (vfrag) {
    vsm[bl][col] = val;
    __syncthreads();
    if (tid < 64) {
      bf16x8 pk;
#pragma unroll
      for (int t = 0; t < 8; ++t)
        pk[t] = f2bf(vsm[(tid >> 4) * 8 + t][tid & 15]);
      ((bf16x8*)vfrag)[(size_t)blockIdx.x * 64 + tid] = pk;
    }
  }
}

// ---- agree: per r-pair M[16x160] = x_r^T @ v (K=B=512, 4 waves x 128),
// then bias[r,j] += (1/B) sum_{i,o} W*M, fused. grid 576 x 256.
__global__ __launch_bounds__(256) void agree_kernel(
    const short* __restrict__ xtf, const float* __restrict__ W,
    const short* __restrict__ vfrag, float* __restrict__ bias) {
  __shared__ float Msm[4][16][176];
  __shared__ float red[320];
  const int tid = threadIdx.x;
  const int w = tid >> 6, lane = tid & 63;
  const int rp = blockIdx.x;
  const int r0 = rp * 2;

  f32x4 acc[10] = {};
  const bf16x8* ap = (const bf16x8*)xtf + ((size_t)rp * 16 + w * 4) * 64 + lane;
  const bf16x8* bp = (const bf16x8*)vfrag + ((size_t)(w * 4) * 640 + lane);
#pragma unroll
  for (int ks = 0; ks < 4; ++ks) {
    bf16x8 af = ap[0];
    ap += 64;
#pragma unroll
    for (int nb = 0; nb < 10; ++nb)
      acc[nb] = __builtin_amdgcn_mfma_f32_16x16x32_bf16(af, bp[nb * 64],
                                                        acc[nb], 0, 0, 0);
    bp += 640;
  }
  {
    int colc = lane & 15, rbase = (lane >> 4) * 4;
#pragma unroll
    for (int nb = 0; nb < 10; ++nb)
#pragma unroll
      for (int q = 0; q < 4; ++q)
        Msm[w][rbase + q][nb * 16 + colc] = acc[nb][q];
  }
  __syncthreads();
  for (int idx = tid; idx < 320; idx += 256) {
    int rr = idx / 160, jo = idx - rr * 160;
    int j = jo >> 4, o = jo & 15;
    float p = 0.0f;
    const float* wp = W + (((size_t)(r0 + rr) * 10 + j) * 16 + o) * 8;
#pragma unroll
    for (int i = 0; i < 8; ++i) {
      float m = Msm[0][rr * 8 + i][jo] + Msm[1][rr * 8 + i][jo] +
                Msm[2][rr * 8 + i][jo] + Msm[3][rr * 8 + i][jo];
      p += wp[i] * m;
    }
    red[idx] = p;
  }
  __syncthreads();
  if (tid < 20) {
    int rr = tid / 10, j = tid - rr * 10;
    float s = 0.0f;
#pragma unroll
    for (int o = 0; o < 16; ++o) s += red[rr * 160 + j * 16 + o];
    bias[(r0 + rr) * 10 + j] += s * (1.0f / 512.0f);
  }
}

// softmax over routes per j; fixed-order tree reductions (deterministic)
__global__ __launch_bounds__(256) void softmax_kernel(
    const float* __restrict__ bias, float* __restrict__ c) {
  __shared__ float red[256];
  const int j = blockIdx.x;
  const int tid = threadIdx.x;
  float m = -1e30f;
  for (int r = tid; r < R_; r += 256) m = fmaxf(m, bias[r * 10 + j]);
  red[tid] = m;
  __syncthreads();
  for (int s = 128; s > 0; s >>= 1) {
    if (tid < s) red[tid] = fmaxf(red[tid], red[tid + s]);
    __syncthreads();
  }
  m = red[0];
  __syncthreads();
  float sum = 0.0f;
  for (int r = tid; r < R_; r += 256) sum += expf(bias[r * 10 + j] - m);
  red[tid] = sum;
  __syncthreads();
  for (int s = 128; s > 0; s >>= 1) {
    if (tid < s) red[tid] += red[tid + s];
    __syncthreads();
  }
  float inv = 1.0f / red[0];
  for (int r = tid; r < R_; r += 256)
    c[r * 10 + j] = expf(bias[r * 10 + j] - m) * inv;
}

extern "C" void kernel_launch(void* const* d_in, const int* in_sizes, int n_in,
                              void* d_out, int out_size, void* d_ws,
                              size_t ws_size, hipStream_t stream) {
  const float* x = (const float*)d_in[0];  // [512,1152,8]
  const float* W = (const float*)d_in[1];  // [1152,10,16,8]
  float* out = (float*)d_out;              // [512][160]
  char* ws = (char*)d_ws;

  // layout (bytes):
  float* bias  = (float*)(ws);             // 46080
  float* c     = (float*)(ws + 46080);     // 46080
  short* vfrag = (short*)(ws + 92160);     // 163840
  short* wcf   = (short*)(ws + 256000);    // 2949120
  short* xaf   = (short*)(ws + 3205120);   // 9437184
  short* xtf   = (short*)(ws + 12642304);  // 9437184
  float* part  = (float*)(ws + 22079488);  // 8*327680 = 2621440

  init_kernel<<<45, 256, 0, stream>>>(bias, c);
  xafbuild_kernel<<<2304, 256, 0, stream>>>(x, xaf);
  xtfbuild_kernel<<<2304, 256, 0, stream>>>(x, xtf);

  for (int it = 0; it < 3; ++it) {
    wcbuild_kernel<<<720, 256, 0, stream>>>(W, c, wcf);
    sgemm_kernel<<<dim3(32, KS_), 256, 0, stream>>>(xaf, wcf, part);
    short* vf = (it < 2) ? vfrag : nullptr;
    float* o = (it == 2) ? out : nullptr;
    squash_kernel<<<160, 512, 0, stream>>>(part, vf, o);
    if (it < 2) {
      agree_kernel<<<576, 256, 0, stream>>>(xtf, W, vfrag, bias);
      softmax_kernel<<<10, 256, 0, stream>>>(bias, c);
    }
  }
}

// Round 11
// 87.017 us; speedup vs baseline: 9.0707x; 1.1348x over previous
//
#include <hip/hip_runtime.h>

// DigitCaps routing via MFMA, u_hat never materialized. Multi-kernel,
// 11 dispatches (boundaries cost ~2.5us each; persistent grid barriers
// proved >=27us each on 8 non-coherent XCDs - r7/r8).
// B=512, R=1152, J=10, O=16, I=8, JO=160, K=R*I=9216.
// s[b,jo]    = sum_k x[b,k] * Wc[k,jo],  Wc[(r,i),(j,o)] = W[r,j,o,i]*c[r,j]
// v          = s*|s|/(1+s^2)
// biasT[j,r]+= (1/B) sum_{i,o} W[r,j,o,i] * M[(r,i),(j,o)],  M = x_r^T @ v
// c          = softmax_r(biasT)  (fused into wcstat via coalesced [j][r] reads)
//
// sgemm: 4 waves/block share one wcf k-slice (L1 reuse x4, r4 geometry) and
// write part in tiled [ks][nb][kb][32][16] layout (r10) so squash reads are
// contiguous. All reductions fixed-order -> deterministic.

#define B_   512
#define R_   1152
#define JO_  160
#define K_   9216
#define KS_  32
#define SPK_ 9

typedef __attribute__((ext_vector_type(4))) float f32x4;
typedef __attribute__((ext_vector_type(8))) short bf16x8;

__device__ __forceinline__ short f2bf(float f) {
  unsigned int u = __float_as_uint(f);
  unsigned int r = (u + 0x7FFFu + ((u >> 16) & 1u)) >> 16;
  return (short)r;
}

// ---- prep: biasT=0, xaf (s-GEMM A-frags), xtf (agree A/B-frags), wcf it0.
// grid 2304 x 256.
__global__ __launch_bounds__(256) void prep_kernel(
    const float* __restrict__ x, const float* __restrict__ W,
    short* __restrict__ xaf, short* __restrict__ xtf,
    short* __restrict__ wcf, float* __restrict__ biasT) {
  int gid = blockIdx.x * 256 + threadIdx.x;  // < 589824
  if (gid < R_ * 10) biasT[gid] = 0.0f;
  {  // xaf: frag f = m16*288+ks; lane l: row m16*16+(l&15), k=ks*32+(l>>4)*8+t
    int l = gid & 63, f = gid >> 6;
    int ks = f % 288, m16 = f / 288;
    int row = m16 * 16 + (l & 15);
    int k0 = ks * 32 + (l >> 4) * 8;
    const float4* p = (const float4*)(x + (size_t)row * K_ + k0);
    float4 a = p[0], b = p[1];
    bf16x8 pk;
    pk[0] = f2bf(a.x); pk[1] = f2bf(a.y); pk[2] = f2bf(a.z); pk[3] = f2bf(a.w);
    pk[4] = f2bf(b.x); pk[5] = f2bf(b.y); pk[6] = f2bf(b.z); pk[7] = f2bf(b.w);
    ((bf16x8*)xaf)[gid] = pk;
  }
  {  // xtf: frag f = rp*16+kb; lane l: row (l&15) of r-pair rp, k=b
    int l = gid & 63, f = gid >> 6;
    int kb = f & 15, rp = f >> 4;
    int b0 = kb * 32 + (l >> 4) * 8;
    const float* p = x + (size_t)b0 * K_ + rp * 16 + (l & 15);
    bf16x8 pk;
#pragma unroll
    for (int t = 0; t < 8; ++t) pk[t] = f2bf(p[(size_t)t * K_]);
    ((bf16x8*)xtf)[gid] = pk;
  }
  if (gid < 184320) {  // wcf iter0: unscaled W (c=1/R folded in sgemm epilogue)
    int l = gid & 63;
    int rest = gid >> 6;
    int nb = rest % 10, kb = rest / 10;
    int r = kb * 4 + (l >> 4);
    int o = l & 15;
    const float4* wp = (const float4*)(W + (((size_t)r * 10 + nb) * 16 + o) * 8);
    float4 a = wp[0], b = wp[1];
    bf16x8 pk;
    pk[0] = f2bf(a.x); pk[1] = f2bf(a.y); pk[2] = f2bf(a.z); pk[3] = f2bf(a.w);
    pk[4] = f2bf(b.x); pk[5] = f2bf(b.y); pk[6] = f2bf(b.z); pk[7] = f2bf(b.w);
    ((bf16x8*)wcf)[gid] = pk;
  }
}

// ---- wcstat: softmax stats (coalesced biasT[j][r] reads, redundant per
// block, fixed order) + Wc build. grid 720 x 256.
__global__ __launch_bounds__(256) void wcstat_kernel(
    const float* __restrict__ W, const float* __restrict__ biasT,
    short* __restrict__ wcf) {
  __shared__ float mzs[20];
  const int tid = threadIdx.x;
  const int w = tid >> 6, lane = tid & 63;
  for (int j = w; j < 10; j += 4) {
    float pv[18];
#pragma unroll
    for (int t = 0; t < 18; ++t) pv[t] = biasT[j * R_ + t * 64 + lane];
    float m = -1e30f;
#pragma unroll
    for (int t = 0; t < 18; ++t) m = fmaxf(m, pv[t]);
#pragma unroll
    for (int d = 32; d; d >>= 1) m = fmaxf(m, __shfl_xor(m, d));
    float s = 0.0f;
#pragma unroll
    for (int t = 0; t < 18; ++t) s += expf(pv[t] - m);
#pragma unroll
    for (int d = 32; d; d >>= 1) s += __shfl_xor(s, d);
    if (lane == 0) {
      mzs[j] = m;
      mzs[10 + j] = 1.0f / s;
    }
  }
  __syncthreads();
  int idx = blockIdx.x * 256 + tid;  // < 184320
  int l = idx & 63;
  int rest = idx >> 6;
  int nb = rest % 10, kb = rest / 10;
  int r = kb * 4 + (l >> 4);
  int o = l & 15;
  const float4* wp = (const float4*)(W + (((size_t)r * 10 + nb) * 16 + o) * 8);
  float4 a = wp[0], b = wp[1];
  float cs = expf(biasT[nb * R_ + r] - mzs[nb]) * mzs[10 + nb];
  bf16x8 pk;
  pk[0] = f2bf(a.x * cs); pk[1] = f2bf(a.y * cs);
  pk[2] = f2bf(a.z * cs); pk[3] = f2bf(a.w * cs);
  pk[4] = f2bf(b.x * cs); pk[5] = f2bf(b.y * cs);
  pk[6] = f2bf(b.z * cs); pk[7] = f2bf(b.w * cs);
  ((bf16x8*)wcf)[idx] = pk;
}

// ---- s-GEMM: grid (8, 32); 4 waves share one 9-step wcf k-slice (L1 reuse),
// wave = one m16-tile x 160. Tiled part writes.
template <bool SCALE>
__global__ __launch_bounds__(256) void sgemm_kernel(
    const short* __restrict__ xaf, const short* __restrict__ wcf,
    float* __restrict__ part) {
  const int tid = threadIdx.x;
  const int w = tid >> 6, lane = tid & 63;
  const int m16 = blockIdx.x * 4 + w;
  const int ks0 = blockIdx.y * SPK_;

  f32x4 acc[10] = {};
  const bf16x8* ap = (const bf16x8*)xaf + ((size_t)m16 * 288 + ks0) * 64 + lane;
  const bf16x8* bp = (const bf16x8*)wcf + ((size_t)ks0 * 640 + lane);
  for (int st = 0; st < SPK_; ++st) {
    bf16x8 af = ap[0];
    ap += 64;
#pragma unroll
    for (int nb = 0; nb < 10; ++nb)
      acc[nb] = __builtin_amdgcn_mfma_f32_16x16x32_bf16(af, bp[nb * 64],
                                                        acc[nb], 0, 0, 0);
    bp += 640;
  }
  // C/D: col=lane&15, row=(lane>>4)*4+q; dest part[ks][nb][kb][32][16]
  const float scale = SCALE ? (1.0f / 1152.0f) : 1.0f;
  const int kb = m16 >> 1;
  const int bl0 = (m16 & 1) * 16 + (lane >> 4) * 4;
  const int colc = lane & 15;
#pragma unroll
  for (int nb = 0; nb < 10; ++nb)
#pragma unroll
    for (int q = 0; q < 4; ++q)
      part[((((size_t)blockIdx.y * 10 + nb) * 16 + kb) * 32 + bl0 + q) * 16 +
           colc] = acc[nb][q] * scale;
}

// ---- squash: reduce 32 tiled planes + squash; grid 160 (one (kb,nb) tile),
// block 512, 1 element/thread; per-plane reads are contiguous 2KB runs.
__global__ __launch_bounds__(512) void squash_kernel(
    const float* __restrict__ part, short* __restrict__ vfrag,
    float* __restrict__ out) {
  __shared__ float vsm[32][17];
  const int tid = threadIdx.x;  // 0..511
  const int kb = blockIdx.x / 10, nb = blockIdx.x - (blockIdx.x / 10) * 10;
  const int bl = tid >> 4, col = tid & 15;
  const float* pe = part + (((size_t)nb * 16 + kb) * 32 + bl) * 16 + col;
  float pv[KS_];
#pragma unroll
  for (int ks = 0; ks < KS_; ++ks) pv[ks] = pe[(size_t)ks * (B_ * JO_)];
  float s = 0.0f;
#pragma unroll
  for (int ks = 0; ks < KS_; ++ks) s += pv[ks];
  float val = s * fabsf(s) / (1.0f + s * s);
  if (out) out[(size_t)(kb * 32 + bl) * JO_ + nb * 16 + col] = val;
  if (vfrag) {
    vsm[bl][col] = val;
    __syncthreads();
    if (tid < 64) {
      bf16x8 pk;
#pragma unroll
      for (int t = 0; t < 8; ++t)
        pk[t] = f2bf(vsm[(tid >> 4) * 8 + t][tid & 15]);
      ((bf16x8*)vfrag)[(size_t)blockIdx.x * 64 + tid] = pk;
    }
  }
}

// ---- agree: per r-pair M[16x160] = x_r^T @ v (K=B=512, 4 waves x 128),
// then biasT[j][r] += (1/B) sum_{i,o} W*M, fused. grid 576 x 256.
__global__ __launch_bounds__(256) void agree_kernel(
    const short* __restrict__ xtf, const float* __restrict__ W,
    const short* __restrict__ vfrag, float* __restrict__ biasT) {
  __shared__ float Msm[4][16][176];
  __shared__ float red[320];
  const int tid = threadIdx.x;
  const int w = tid >> 6, lane = tid & 63;
  const int rp = blockIdx.x;
  const int r0 = rp * 2;

  f32x4 acc[10] = {};
  const bf16x8* ap = (const bf16x8*)xtf + ((size_t)rp * 16 + w * 4) * 64 + lane;
  const bf16x8* bp = (const bf16x8*)vfrag + ((size_t)(w * 4) * 640 + lane);
#pragma unroll
  for (int ks = 0; ks < 4; ++ks) {
    bf16x8 af = ap[0];
    ap += 64;
#pragma unroll
    for (int nb = 0; nb < 10; ++nb)
      acc[nb] = __builtin_amdgcn_mfma_f32_16x16x32_bf16(af, bp[nb * 64],
                                                        acc[nb], 0, 0, 0);
    bp += 640;
  }
  {
    int colc = lane & 15, rbase = (lane >> 4) * 4;
#pragma unroll
    for (int nb = 0; nb < 10; ++nb)
#pragma unroll
      for (int q = 0; q < 4; ++q)
        Msm[w][rbase + q][nb * 16 + colc] = acc[nb][q];
  }
  __syncthreads();
  for (int idx = tid; idx < 320; idx += 256) {
    int rr = idx / 160, jo = idx - rr * 160;
    int j = jo >> 4, o = jo & 15;
    float p = 0.0f;
    const float* wp = W + (((size_t)(r0 + rr) * 10 + j) * 16 + o) * 8;
#pragma unroll
    for (int i = 0; i < 8; ++i) {
      float m = Msm[0][rr * 8 + i][jo] + Msm[1][rr * 8 + i][jo] +
                Msm[2][rr * 8 + i][jo] + Msm[3][rr * 8 + i][jo];
      p += wp[i] * m;
    }
    red[idx] = p;
  }
  __syncthreads();
  if (tid < 20) {
    int rr = tid / 10, j = tid - rr * 10;
    float s = 0.0f;
#pragma unroll
    for (int o = 0; o < 16; ++o) s += red[rr * 160 + j * 16 + o];
    biasT[j * R_ + (r0 + rr)] += s * (1.0f / 512.0f);
  }
}

extern "C" void kernel_launch(void* const* d_in, const int* in_sizes, int n_in,
                              void* d_out, int out_size, void* d_ws,
                              size_t ws_size, hipStream_t stream) {
  const float* x = (const float*)d_in[0];  // [512,1152,8]
  const float* W = (const float*)d_in[1];  // [1152,10,16,8]
  float* out = (float*)d_out;              // [512][160]
  char* ws = (char*)d_ws;

  // layout (bytes):
  float* biasT = (float*)(ws);             // 46080
  short* vfrag = (short*)(ws + 46080);     // 163840
  short* wcf   = (short*)(ws + 209920);    // 2949120
  short* xaf   = (short*)(ws + 3159040);   // 9437184
  short* xtf   = (short*)(ws + 12596224);  // 9437184
  float* part  = (float*)(ws + 22033408);  // 32*327680 = 10485760

  prep_kernel<<<2304, 256, 0, stream>>>(x, W, xaf, xtf, wcf, biasT);

  // iter 0 (c uniform, folded as 1/1152 epilogue scale; wcf from prep)
  sgemm_kernel<true><<<dim3(8, KS_), 256, 0, stream>>>(xaf, wcf, part);
  squash_kernel<<<160, 512, 0, stream>>>(part, vfrag, nullptr);
  agree_kernel<<<576, 256, 0, stream>>>(xtf, W, vfrag, biasT);
  wcstat_kernel<<<720, 256, 0, stream>>>(W, biasT, wcf);
  // iter 1
  sgemm_kernel<false><<<dim3(8, KS_), 256, 0, stream>>>(xaf, wcf, part);
  squash_kernel<<<160, 512, 0, stream>>>(part, vfrag, nullptr);
  agree_kernel<<<576, 256, 0, stream>>>(xtf, W, vfrag, biasT);
  wcstat_kernel<<<720, 256, 0, stream>>>(W, biasT, wcf);
  // iter 2
  sgemm_kernel<false><<<dim3(8, KS_), 256, 0, stream>>>(xaf, wcf, part);
  squash_kernel<<<160, 512, 0, stream>>>(part, nullptr, out);
}